// Round 21
// baseline (255.934 us; speedup 1.0000x reference)
//
#include <hip/hip_runtime.h>
#include <hip/hip_bf16.h>
#include <math.h>

typedef __attribute__((ext_vector_type(8))) short short8;
typedef __attribute__((ext_vector_type(4))) short short4_t;
typedef __attribute__((ext_vector_type(4))) float f32x4;

__device__ const int d_PERM[9] = {0,2,6,3,7,1,5,8,4};
__device__ const int d_DEG[9]  = {0,1,1,1,2,2,2,2,2};

__device__ __forceinline__ float silu_f(float x){ return x / (1.0f + __expf(-x)); }

__device__ __forceinline__ unsigned short f2bf(float f){
  __hip_bfloat16 h = __float2bfloat16(f);
  return __builtin_bit_cast(unsigned short, h);
}
__device__ __forceinline__ float bf2f(unsigned short b){
  return __uint_as_float(((unsigned int)b) << 16);
}

// flag: 0 = int32 words, 1 = u8 bytes, 2 = float32 words, 3 = int64 (low word)
__device__ __forceinline__ int mask_at(const void* mp, int flag, int e){
  if (flag==1) return ((const unsigned char*)mp)[e] != 0;
  if (flag==3) return ((const unsigned int*)mp)[2*e] != 0u;
  return ((const unsigned int*)mp)[e] != 0u;
}

__global__ void k_detect(const unsigned int* __restrict__ w, int* __restrict__ flag){
  __shared__ int notI, notF, anyOdd, anyEven;
  if (threadIdx.x==0){ notI=0; notF=0; anyOdd=0; anyEven=0; }
  __syncthreads();
  int li=0, lf=0, lo=0, le=0;
  for (int i = threadIdx.x; i < 1024; i += 256){
    unsigned int v = w[i];
    if (v != 0u && v != 1u) li = 1;
    if (v != 0u && v != 0x3F800000u) lf = 1;
    if (v != 0u){ if (i & 1) lo = 1; else le = 1; }
  }
  if (li) atomicOr(&notI,1);
  if (lf) atomicOr(&notF,1);
  if (lo) atomicOr(&anyOdd,1);
  if (le) atomicOr(&anyEven,1);
  __syncthreads();
  if (threadIdx.x==0){
    int f;
    if (!notI) f = (anyOdd || !anyEven) ? 0 : 3;
    else       f = (!notF) ? 2 : 1;
    *flag = f;
  }
}

__global__ __launch_bounds__(256) void k_compact(const void* __restrict__ maskp,
    const int* __restrict__ flagp, int* __restrict__ list, int* __restrict__ count){
  __shared__ int cnt[256];
  __shared__ int offs[256];
  int f = *flagp;
  int tid = threadIdx.x;
  int base = tid*16;
  int c = 0;
  for (int i=0;i<16;i++) if (!mask_at(maskp, f, base+i)) c++;
  cnt[tid] = c;
  __syncthreads();
  if (tid==0){
    int r = 0;
    for (int i=0;i<256;i++){ offs[i] = r; r += cnt[i]; }
    *count = r;
  }
  __syncthreads();
  int w = offs[tid];
  for (int i=0;i<16;i++){
    int e = base+i;
    if (!mask_at(maskp, f, e)) list[w++] = e;
  }
}

// ---------------- H = x @ w_in[DEG] (+b_in at j==0), (N,9,128) ----------------
__global__ __launch_bounds__(128) void k_h(const float* __restrict__ x,
    const float* __restrict__ w_in, const float* __restrict__ b_in,
    float* __restrict__ H){
  __shared__ float xl[16][260];
  int i = blockIdx.y; int n0 = blockIdx.x*16;
  int deg = d_DEG[i];
  for (int idx = threadIdx.x; idx < 16*256; idx += 128){
    int r = idx >> 8, c = idx & 255;
    xl[r][c] = x[((size_t)(n0+r)*9 + i)*256 + c];
  }
  __syncthreads();
  int o = threadIdx.x;
  float acc[16];
  #pragma unroll
  for (int r=0;r<16;r++) acc[r]=0.f;
  const float* w = w_in + (size_t)deg*32768 + o;
  for (int c=0;c<256;c+=4){
    float w0=w[(size_t)c*128], w1=w[(size_t)(c+1)*128], w2=w[(size_t)(c+2)*128], w3=w[(size_t)(c+3)*128];
    #pragma unroll
    for (int r=0;r<16;r++){
      float4 xv4 = *(const float4*)&xl[r][c];
      acc[r] += xv4.x*w0 + xv4.y*w1 + xv4.z*w2 + xv4.w*w3;
    }
  }
  float bb = (i==0)? b_in[o] : 0.f;
  #pragma unroll
  for (int r=0;r<16;r++) H[((size_t)(n0+r)*9+i)*128+o] = acc[r]+bb;
}

// ---------------- XE (E,16) ----------------
__global__ __launch_bounds__(256) void k_xe(const float* __restrict__ attn,
    const float* __restrict__ fdw, const float* __restrict__ fdb,
    const float* __restrict__ few, const float* __restrict__ feb,
    const float* __restrict__ es, const float* __restrict__ et,
    const int* __restrict__ an, const int* __restrict__ esrc,
    float* __restrict__ XE){
  int e = blockIdx.x*256 + threadIdx.x;
  float aw[32];
  #pragma unroll
  for (int k=0;k<32;k+=4){
    float4 v = *(const float4*)&attn[(size_t)e*32+k];
    aw[k]=v.x; aw[k+1]=v.y; aw[k+2]=v.z; aw[k+3]=v.w;
  }
  int src = esrc[e]; int tgt = e>>3;
  int za = an[src], zb = an[tgt];
  float v0[16];
  #pragma unroll
  for (int j=0;j<16;j++){
    float s = fdb[j] + es[(size_t)za*16+j] + et[(size_t)zb*16+j];
    #pragma unroll
    for (int k=0;k<32;k++) s += aw[k]*fdw[k*16+j];
    v0[j] = silu_f(s);
  }
  #pragma unroll
  for (int j=0;j<16;j++){
    float s = feb[j];
    #pragma unroll
    for (int k=0;k<16;k++) s += v0[k]*few[k*16+j];
    XE[(size_t)e*16+j] = silu_f(s);
  }
}

// ============ weight convert + transpose to bf16 [N][K] layouts ============
__global__ __launch_bounds__(256) void k_wcvt(
    const float* __restrict__ m0w1, const float* __restrict__ m1w1r, const float* __restrict__ m1w1i,
    const float* __restrict__ m2w1r, const float* __restrict__ m2w1i,
    const float* __restrict__ m0w2, const float* __restrict__ m1w2r, const float* __restrict__ m1w2i,
    const float* __restrict__ m2w2r, const float* __restrict__ m2w2i,
    unsigned short* __restrict__ Wt)
{
  int base = (blockIdx.x*256 + threadIdx.x)*4;
  #pragma unroll
  for (int ii = 0; ii < 4; ii++){
    int idx = base + ii;
    float v;
    if (idx < 98304){
      int p = idx/49152, r = idx%49152, n = r/384, k = r%384;
      v = m0w1[p*49152 + k*128 + n];
    } else if (idx < 229376){
      int j = idx-98304; int q = j/32768, r = j%32768, n = r/256, k = r%256;
      const float* w = (q&1)?m1w1i:m1w1r;
      v = w[(q>>1)*32768 + k*128 + n];
    } else if (idx < 294912){
      int j = idx-229376; int q = j/16384, r = j%16384, n = r/128, k = r%128;
      const float* w = (q&1)?m2w1i:m2w1r;
      v = w[(q>>1)*16384 + k*128 + n];
    } else if (idx < 393216){
      int j = idx-294912; int n = j/256, k = j%256;
      v = m0w2[(k>>7)*49152 + (k&127)*384 + n];
    } else if (idx < 524288){
      int j = idx-393216; int n = j/512, k = j%512;
      const float* w = ((k>>7)&1)?m1w2i:m1w2r;
      v = w[(k>>8)*32768 + (k&127)*256 + n];
    } else {
      int j = idx-524288; int n = j/512, k = j%512;
      const float* w = ((k>>7)&1)?m2w2i:m2w2r;
      v = w[(k>>8)*16384 + (k&127)*128 + n];
    }
    Wt[idx] = f2bf(v);
  }
}

// ============ grid-coefficient MFMA fragments (zero-padded) ============
__global__ __launch_bounds__(256) void k_fprep(const float* __restrict__ tg,
    const float* __restrict__ fg,
    unsigned short* __restrict__ tgA, unsigned short* __restrict__ fgA)
{
  for (int idx = threadIdx.x; idx < 11264; idx += 256){
    int pt = idx >> 9, rem = idx & 511, l = rem >> 3, j = rem & 7;
    int p = pt*16 + (l & 15);
    int i = (l >> 4)*8 + j;
    float v = (p < 324 && i < 9) ? tg[p*9 + i] : 0.f;
    tgA[idx] = f2bf(v);
  }
  for (int idx = threadIdx.x; idx < 5632; idx += 256){
    int sb = idx >> 9, rem = idx & 511, l = rem >> 3, j = rem & 7;
    int p = sb*32 + (l >> 4)*8 + j;
    int i = l & 15;
    float v = (p < 324 && i < 9) ? fg[p*9 + i] : 0.f;
    fgA[idx] = f2bf(v);
  }
}

// ================= rotate + gates (LDS-staged H, bf16 out, single chunk) ==========
__global__ __launch_bounds__(256) void k_rotgate_m(
    const float* __restrict__ Hg, const float* __restrict__ XEg,
    const int* __restrict__ esrc, const float* __restrict__ wig,
    const float* __restrict__ d0w,  const float* __restrict__ d0b,
    const float* __restrict__ m1dw, const float* __restrict__ m1db,
    const float* __restrict__ m2dw, const float* __restrict__ m2db,
    unsigned short* __restrict__ XSb, unsigned short* __restrict__ XTb,
    unsigned short* __restrict__ Gb,
    const int* __restrict__ list, const int* __restrict__ countp)
{
  int slot = blockIdx.x;
  if (slot >= *countp) return;
  __shared__ float HL[2304];    // hsrc 0..1152 | htgt 1152..2304
  __shared__ float wlr[81];
  __shared__ float xe16[16];
  int e = list[slot];
  int tid = threadIdx.x;
  int n = e >> 3, src = esrc[e];
  if (tid < 16) xe16[tid] = XEg[(size_t)e*16 + tid];
  for (int i = tid; i < 81; i += 256) wlr[i] = wig[(size_t)e*81 + i];
  {
    const float* hs = Hg + (size_t)src*1152;
    const float* ht = Hg + (size_t)n*1152;
    for (int idx = tid; idx < 1152; idx += 256){
      HL[idx]        = hs[idx];
      HL[1152 + idx] = ht[idx];
    }
  }
  __syncthreads();
  for (int idx = tid; idx < 1152; idx += 256){
    int p = idx >> 7, c = idx & 127;
    int ch = d_PERM[p];
    float s1 = 0.f, s2 = 0.f;
    #pragma unroll
    for (int j = 0; j < 9; j++){
      float wv = wlr[ch*9 + j];
      s1 += wv * HL[j*128 + c];
      s2 += wv * HL[1152 + j*128 + c];
    }
    XSb[(size_t)slot*1152 + idx] = f2bf(s1);
    XTb[(size_t)slot*1152 + idx] = f2bf(s2);
  }
  for (int col = tid; col < 1280; col += 256){
    int b = col / 640, r = col % 640;
    const float* w; float bias; int ldw, c2;
    if (r < 128){       w = d0w  + (size_t)b*2048; c2 = r;     ldw = 128; bias = d0b[b*128 + c2]; }
    else if (r < 384){  w = m1dw + (size_t)b*4096; c2 = r-128; ldw = 256; bias = m1db[b*256 + c2]; }
    else {              w = m2dw + (size_t)b*4096; c2 = r-384; ldw = 256; bias = m2db[b*256 + c2]; }
    float s = bias;
    #pragma unroll
    for (int kk = 0; kk < 16; kk++) s += xe16[kk] * w[kk*ldw + c2];
    Gb[(size_t)slot*1280 + col] = f2bf(silu_f(s));
  }
}

// ================= stage-1 MFMA GEMM (single chunk, 4096 slots) =================
__global__ __launch_bounds__(256) void k_gs1m(
    const unsigned short* __restrict__ XSb, const unsigned short* __restrict__ XTb,
    const unsigned short* __restrict__ Gb, const unsigned short* __restrict__ Wt,
    unsigned short* __restrict__ Pgb,
    const int* __restrict__ countp)
{
  int lc = *countp;
  if (lc <= 0) return;
  int b = blockIdx.x, t = threadIdx.x;
  const unsigned short* Ax; const unsigned short* Bw;
  int K, bm, obase, goff, rsh, aoff, tstride;
  if (b < 128){
    int path = b & 1, mt = b >> 1;
    Ax = path ? XTb : XSb;
    Bw = Wt + path*49152;
    K = 384; bm = mt*64; obase = path*128; goff = path ? 640 : 0;
    rsh = 0; aoff = 0; tstride = 0;
  } else if (b < 640){
    int i = b-128; int q = i>>7, mt = i&127;
    Ax = (q>=2) ? XTb : XSb;
    Bw = Wt + 98304 + q*32768;
    K = 256; bm = mt*64; obase = 256 + q*256; goff = 128 + (q&1)*128 + (q>>1)*640;
    rsh = 1; aoff = 384; tstride = 256;
  } else {
    int i = b-640; int q = i>>7, mt = i&127;
    Ax = (q>=2) ? XTb : XSb;
    Bw = Wt + 229376 + q*16384;
    K = 128; bm = mt*64; obase = 1280 + q*256; goff = 384 + (q&1)*128 + (q>>1)*640;
    rsh = 1; aoff = 896; tstride = 128;
  }
  int rows = rsh ? 2*lc : lc;
  if (bm >= rows) return;
  int w = t >> 6, l = t & 63;
  int am = bm + w*16 + (l & 15);
  int ael = am >> rsh, atp = am & rsh;
  const unsigned short* aptr = Ax + (size_t)ael*1152 + aoff + atp*tstride + ((l>>4)*8);
  int bn = l & 15;
  int bko = (l>>4)*8;
  f32x4 acc[8];
  #pragma unroll
  for (int i=0;i<8;i++){ acc[i][0]=0.f; acc[i][1]=0.f; acc[i][2]=0.f; acc[i][3]=0.f; }
  for (int k0 = 0; k0 < K; k0 += 32){
    short8 a = *(const short8*)(aptr + k0);
    #pragma unroll
    for (int nt = 0; nt < 8; nt++){
      const unsigned short* bp = Bw + (size_t)(nt*16 + bn)*K + k0 + bko;
      short8 bb = *(const short8*)bp;
      acc[nt] = __builtin_amdgcn_mfma_f32_16x16x32_bf16(a, bb, acc[nt], 0, 0, 0);
    }
  }
  #pragma unroll
  for (int nt = 0; nt < 8; nt++){
    #pragma unroll
    for (int r = 0; r < 4; r++){
      int i2 = (l>>4)*4 + r;
      int m = bm + w*16 + i2;
      int el = m >> rsh, tp = m & rsh;
      int h = nt*16 + (l & 15);
      float v = acc[nt][r] * bf2f(Gb[(size_t)el*1280 + goff + h]);
      Pgb[(size_t)el*2304 + obase + tp*128 + h] = f2bf(v);
    }
  }
}

// ================= stage-2 MFMA GEMM -> Ybb bf16 [slot][ch][c] (coalesced) =================
__global__ __launch_bounds__(256) void k_gs2m(
    const unsigned short* __restrict__ Pgb, const unsigned short* __restrict__ Wt2,
    unsigned short* __restrict__ Ybb,
    const int* __restrict__ countp)
{
  int lc = *countp;
  if (lc <= 0) return;
  int b = blockIdx.x, t = threadIdx.x;
  int region, bm, ncb, K, rsh, segb;
  const unsigned short* Bw;
  if (b < 192){ region=0; int mt=b/3, nt3=b-mt*3; bm=mt*64; ncb=nt3*128; K=256; rsh=0; segb=0;    Bw = Wt2; }
  else if (b < 448){ region=1; int i=b-192; int mt=i>>1, nt2=i&1; bm=mt*64; ncb=nt2*128; K=512; rsh=1; segb=256;  Bw = Wt2 + 98304; }
  else { region=2; int mt=b-448; bm=mt*64; ncb=0; K=512; rsh=1; segb=1280; Bw = Wt2 + 229376; }
  int rows = rsh ? 2*lc : lc;
  if (bm >= rows) return;
  int w = t >> 6, l = t & 63;
  int am = bm + w*16 + (l & 15);
  int ael = am >> rsh, atp = am & rsh;
  int bko = (l>>4)*8;
  f32x4 acc[8];
  #pragma unroll
  for (int i=0;i<8;i++){ acc[i][0]=0.f; acc[i][1]=0.f; acc[i][2]=0.f; acc[i][3]=0.f; }
  for (int k0 = 0; k0 < K; k0 += 32){
    const unsigned short* ap;
    short sm = 0;
    if (region == 0){
      ap = Pgb + (size_t)ael*2304 + k0 + bko;
    } else {
      int seg = k0 >> 7, kk = k0 & 127;
      int tsel = (seg&1) ? (1-atp) : atp;
      sm = (short)(((seg&1) && atp==0) ? 0x8000 : 0);
      ap = Pgb + (size_t)ael*2304 + segb + seg*256 + tsel*128 + kk + bko;
    }
    short8 a = *(const short8*)ap;
    short8 smv = (short8)sm;
    a ^= smv;
    #pragma unroll
    for (int nt = 0; nt < 8; nt++){
      const unsigned short* bp = Bw + (size_t)(ncb + nt*16 + (l&15))*K + k0 + bko;
      short8 bb = *(const short8*)bp;
      acc[nt] = __builtin_amdgcn_mfma_f32_16x16x32_bf16(a, bb, acc[nt], 0, 0, 0);
    }
  }
  #pragma unroll
  for (int nt = 0; nt < 8; nt++){
    #pragma unroll
    for (int r = 0; r < 4; r++){
      int i2 = (l>>4)*4 + r;
      int m = bm + w*16 + i2;
      int el = m >> rsh, tp = m & rsh;
      int col = ncb + nt*16 + (l&15);
      int g = col >> 7, c = col & 127;
      int ch;
      if (region==0)      ch = (g==0) ? 0 : ((g==1) ? 2 : 6);
      else if (region==1) ch = tp ? (g ? 5 : 1) : (g ? 7 : 3);
      else                ch = tp ? 4 : 8;
      Ybb[(size_t)el*1152 + ch*128 + c] = f2bf(acc[nt][r]);
    }
  }
}

// ================= MFMA grid transform: dual ct-chain interleave =================
__global__ __launch_bounds__(256) void k_gridm(
    const unsigned short* __restrict__ Ybb,
    const unsigned short* __restrict__ tgA, const unsigned short* __restrict__ fgA,
    const float* __restrict__ wig,
    const int* __restrict__ list, const int* __restrict__ countp,
    float* __restrict__ R)
{
  int slot = blockIdx.x;
  if (slot >= *countp) return;
  __shared__ float wl[81];
  __shared__ unsigned short YL[128*24];
  __shared__ unsigned short Sld[2][4][640];   // [ct][wave][c(16) stride 40 p32(32)]
  __shared__ float Zld[4][256];               // per wave: [c(16)][i(16)] (reused ct0 then ct1)
  int tid = threadIdx.x;
  int e = list[slot];
  for (int i = tid; i < 81; i += 256) wl[i] = wig[(size_t)e*81 + i];
  for (int i = tid; i < 3072; i += 256) YL[i] = 0;
  __syncthreads();
  const unsigned short* ybase = Ybb + (size_t)slot*1152;
  for (int idx = tid; idx < 1152; idx += 256){
    int ch = idx >> 7, c = idx & 127;
    YL[c*24 + ch] = ybase[idx];
  }
  __syncthreads();
  int w = tid >> 6, l = tid & 63;
  int lcn = l & 15, lg = l >> 4;
  int c0a = (w*2 + 0)*16;
  int c0b = (w*2 + 1)*16;

  short8 bfA0 = (short8)(short)0, bfA1 = (short8)(short)0;
  if (lg < 2){
    bfA0 = *(const short8*)(&YL[(c0a + lcn)*24 + lg*8]);
    bfA1 = *(const short8*)(&YL[(c0b + lcn)*24 + lg*8]);
  }
  f32x4 Z0, Z1;
  Z0[0]=0.f; Z0[1]=0.f; Z0[2]=0.f; Z0[3]=0.f;
  Z1 = Z0;
  for (int sb = 0; sb < 11; sb++){
    f32x4 zr; zr[0]=0.f; zr[1]=0.f; zr[2]=0.f; zr[3]=0.f;
    short8 a0 = *(const short8*)(tgA + (size_t)(sb*2+0)*512 + l*8);
    short8 a1 = *(const short8*)(tgA + (size_t)(sb*2+1)*512 + l*8);
    f32x4 s00 = __builtin_amdgcn_mfma_f32_16x16x32_bf16(a0, bfA0, zr, 0, 0, 0);
    f32x4 s10 = __builtin_amdgcn_mfma_f32_16x16x32_bf16(a1, bfA0, zr, 0, 0, 0);
    f32x4 s01 = __builtin_amdgcn_mfma_f32_16x16x32_bf16(a0, bfA1, zr, 0, 0, 0);
    f32x4 s11 = __builtin_amdgcn_mfma_f32_16x16x32_bf16(a1, bfA1, zr, 0, 0, 0);
    short4_t pk00, pk10, pk01, pk11;
    #pragma unroll
    for (int r = 0; r < 4; r++){
      float v00 = s00[r]; v00 = v00 * __fdividef(1.0f, 1.0f + __expf(-v00));
      float v10 = s10[r]; v10 = v10 * __fdividef(1.0f, 1.0f + __expf(-v10));
      float v01 = s01[r]; v01 = v01 * __fdividef(1.0f, 1.0f + __expf(-v01));
      float v11 = s11[r]; v11 = v11 * __fdividef(1.0f, 1.0f + __expf(-v11));
      pk00[r] = (short)f2bf(v00);
      pk10[r] = (short)f2bf(v10);
      pk01[r] = (short)f2bf(v01);
      pk11[r] = (short)f2bf(v11);
    }
    *(short4_t*)&Sld[0][w][lcn*40 + lg*4]      = pk00;
    *(short4_t*)&Sld[0][w][lcn*40 + 16 + lg*4] = pk10;
    *(short4_t*)&Sld[1][w][lcn*40 + lg*4]      = pk01;
    *(short4_t*)&Sld[1][w][lcn*40 + 16 + lg*4] = pk11;
    short8 af = *(const short8*)(fgA + (size_t)sb*512 + l*8);
    short8 bs0 = *(const short8*)&Sld[0][w][lcn*40 + lg*8];
    short8 bs1 = *(const short8*)&Sld[1][w][lcn*40 + lg*8];
    Z0 = __builtin_amdgcn_mfma_f32_16x16x32_bf16(af, bs0, Z0, 0, 0, 0);
    Z1 = __builtin_amdgcn_mfma_f32_16x16x32_bf16(af, bs1, Z1, 0, 0, 0);
  }
  // stage D ct0
  {
    *(f32x4*)&Zld[w][lcn*16 + lg*4] = Z0;
    float zc[9];
    #pragma unroll
    for (int j = 0; j < 9; j++) zc[j] = Zld[w][lcn*16 + j];
    #pragma unroll
    for (int t2 = 0; t2 < 3; t2++){
      int i2 = lg + t2*4;
      if (i2 < 9){
        float r = 0.f;
        #pragma unroll
        for (int j = 0; j < 9; j++) r += wl[j*9 + i2] * zc[j];
        R[(size_t)e*1152 + i2*128 + c0a + lcn] = r;
      }
    }
  }
  // stage D ct1 (wave-local reuse of Zld; program order guarantees ordering)
  {
    *(f32x4*)&Zld[w][lcn*16 + lg*4] = Z1;
    float zc[9];
    #pragma unroll
    for (int j = 0; j < 9; j++) zc[j] = Zld[w][lcn*16 + j];
    #pragma unroll
    for (int t2 = 0; t2 < 3; t2++){
      int i2 = lg + t2*4;
      if (i2 < 9){
        float r = 0.f;
        #pragma unroll
        for (int j = 0; j < 9; j++) r += wl[j*9 + i2] * zc[j];
        R[(size_t)e*1152 + i2*128 + c0b + lcn] = r;
      }
    }
  }
}

// ================= masked reduce + w_out projection =================
__global__ __launch_bounds__(256) void k_redout2(const float* __restrict__ R,
    const void* __restrict__ maskp, const int* __restrict__ flagp,
    const float* __restrict__ w_out, const float* __restrict__ b_out,
    float* __restrict__ out){
  __shared__ float sacc[128];
  int i2 = blockIdx.x; int n = blockIdx.y;
  int tid = threadIdx.x;
  int f = *flagp;
  if (tid < 128){
    float a = 0.f;
    for (int k = 0; k < 8; k++){
      int e = n*8 + k;
      if (!mask_at(maskp, f, e)) a += R[(size_t)e*1152 + i2*128 + tid];
    }
    sacc[tid] = a;
  }
  __syncthreads();
  int o = tid;
  int deg = d_DEG[i2];
  const float* wp = w_out + (size_t)deg*32768 + o;
  float s = (i2==0) ? b_out[o] : 0.f;
  #pragma unroll 4
  for (int c = 0; c < 128; c += 4){
    float4 a = *(const float4*)&sacc[c];
    s += a.x*wp[(size_t)c*256] + a.y*wp[(size_t)(c+1)*256]
       + a.z*wp[(size_t)(c+2)*256] + a.w*wp[(size_t)(c+3)*256];
  }
  out[((size_t)n*9 + i2)*256 + o] = s;
}

// ================= fallback mega kernel (round-5, pass-verified) =================
__device__ __forceinline__ float dotW(const float* __restrict__ A, const float* __restrict__ Wm, int K){
  float s = 0.f;
  #pragma unroll 4
  for (int i=0;i<K;i+=4){
    float4 a = *(const float4*)&A[i];
    s += a.x*Wm[(size_t)i*128] + a.y*Wm[(size_t)(i+1)*128]
       + a.z*Wm[(size_t)(i+2)*128] + a.w*Wm[(size_t)(i+3)*128];
  }
  return s;
}
__device__ __forceinline__ float dot2W(const float* __restrict__ P0, const float* __restrict__ P1,
    const float* __restrict__ W0, const float* __restrict__ W1, int ldw){
  float s = 0.f;
  #pragma unroll 4
  for (int k=0;k<128;k+=4){
    float4 a = *(const float4*)&P0[k];
    float4 b = *(const float4*)&P1[k];
    s += a.x*W0[(size_t)k*ldw] + a.y*W0[(size_t)(k+1)*ldw] + a.z*W0[(size_t)(k+2)*ldw] + a.w*W0[(size_t)(k+3)*ldw];
    s += b.x*W1[(size_t)k*ldw] + b.y*W1[(size_t)(k+1)*ldw] + b.z*W1[(size_t)(k+2)*ldw] + b.w*W1[(size_t)(k+3)*ldw];
  }
  return s;
}

__global__ __launch_bounds__(256) void k_mega(
    const float* __restrict__ x,      const float* __restrict__ w_in,  const float* __restrict__ b_in,
    const float* __restrict__ attn,
    const float* __restrict__ fdw,    const float* __restrict__ fdb,
    const float* __restrict__ few,    const float* __restrict__ feb,
    const float* __restrict__ es,     const float* __restrict__ et,
    const int*   __restrict__ an,     const int*   __restrict__ esrc,
    const float* __restrict__ d0w,    const float* __restrict__ d0b,
    const float* __restrict__ m1dw,   const float* __restrict__ m1db,
    const float* __restrict__ m2dw,   const float* __restrict__ m2db,
    const float* __restrict__ m0w1,   const float* __restrict__ m0w2,
    const float* __restrict__ m1w1r,  const float* __restrict__ m1w2r,
    const float* __restrict__ m1w1i,  const float* __restrict__ m1w2i,
    const float* __restrict__ m2w1r,  const float* __restrict__ m2w2r,
    const float* __restrict__ m2w1i,  const float* __restrict__ m2w2i,
    const float* __restrict__ wig,    const float* __restrict__ tg,   const float* __restrict__ fg,
    const float* __restrict__ w_out,  const float* __restrict__ b_out,
    const void*  __restrict__ maskp,  const int* __restrict__ flagp,
    float* __restrict__ out)
{
  __shared__ float S[7168];
  float* acc  = S;
  float* xs   = S + 1152;
  float* xtl  = S + 2304;
  float* Zb   = S + 1152;
  float* gg   = S + 3456;
  float* Yb   = S + 3456;
  float* P    = S + 4736;
  float* wl   = S + 7040;
  float* xe16 = S + 7124;
  float* xv   = S + 7140;

  const int n   = blockIdx.x;
  const int tid = threadIdx.x;
  const int f   = *flagp;

  for (int i = tid; i < 1152; i += 256) acc[i] = 0.f;

  for (int k = 0; k < 8; k++){
    int e = n*8 + k;
    if (mask_at(maskp, f, e)) continue;
    int src = esrc[e];
    __syncthreads();
    for (int i = tid; i < 81; i += 256) wl[i] = wig[(size_t)e*81 + i];
    if (tid < 16){
      int j = tid;
      float s = fdb[j] + es[(size_t)an[src]*16 + j] + et[(size_t)an[n]*16 + j];
      for (int kk = 0; kk < 32; kk++) s += attn[(size_t)e*32 + kk] * fdw[kk*16 + j];
      xv[j] = silu_f(s);
    }
    for (int idx = tid; idx < 2304; idx += 256){
      int which = idx >= 1152;
      int lidx = idx - which*1152;
      int j = lidx >> 7, c = lidx & 127;
      int deg = d_DEG[j];
      const float* wp = w_in + (size_t)deg*32768 + c;
      const float* xp = x + ((size_t)(which ? n : src)*9 + j)*256;
      float s = (j==0) ? b_in[c] : 0.f;
      for (int cc = 0; cc < 256; cc++) s += xp[cc] * wp[cc*128];
      P[idx] = s;
    }
    __syncthreads();
    if (tid < 16){
      int j = tid;
      float s = feb[j];
      for (int kk = 0; kk < 16; kk++) s += xv[kk] * few[kk*16 + j];
      xe16[j] = silu_f(s);
    }
    for (int idx = tid; idx < 1152; idx += 256){
      int p = idx >> 7, c = idx & 127;
      int ch = d_PERM[p];
      float s1 = 0.f, s2 = 0.f;
      #pragma unroll
      for (int j = 0; j < 9; j++){
        float wv = wl[ch*9 + j];
        s1 += wv * P[j*128 + c];
        s2 += wv * P[1152 + j*128 + c];
      }
      xs[idx]  = s1;
      xtl[idx] = s2;
    }
    __syncthreads();
    for (int col = tid; col < 1280; col += 256){
      int b = col / 640, r = col % 640;
      const float* w; float bias; int ldw, c2;
      if (r < 128){       w = d0w  + (size_t)b*2048; c2 = r;     ldw = 128; bias = d0b[b*128 + c2]; }
      else if (r < 384){  w = m1dw + (size_t)b*4096; c2 = r-128; ldw = 256; bias = m1db[b*256 + c2]; }
      else {              w = m2dw + (size_t)b*4096; c2 = r-384; ldw = 256; bias = m2db[b*256 + c2]; }
      float s = bias;
      #pragma unroll
      for (int kk = 0; kk < 16; kk++) s += xe16[kk] * w[kk*ldw + c2];
      gg[col] = silu_f(s);
    }
    __syncthreads();
    for (int o = tid; o < 2304; o += 256){
      float s;
      if (o < 256){
        int path = o >> 7, h = o & 127;
        s = dotW(path ? xtl : xs, m0w1 + (size_t)path*49152 + h, 384);
      } else if (o < 1280){
        int q = (o-256) >> 8; int rem = (o-256) & 255; int t = rem >> 7, h = rem & 127;
        const float* A  = ((q>=2) ? xtl : xs) + 384 + t*256;
        const float* Wm = ((q&1) ? m1w1i : m1w1r) + (size_t)((q>=2)?1:0)*32768 + h;
        s = dotW(A, Wm, 256);
      } else {
        int q = (o-1280) >> 8; int rem = (o-1280) & 255; int t = rem >> 7, h = rem & 127;
        const float* A  = ((q>=2) ? xtl : xs) + 896 + t*128;
        const float* Wm = ((q&1) ? m2w1i : m2w1r) + (size_t)((q>=2)?1:0)*16384 + h;
        s = dotW(A, Wm, 128);
      }
      P[o] = s;
    }
    __syncthreads();
    for (int o = tid; o < 2304; o += 256){
      int h = o & 127, goff;
      if (o < 256) goff = (o >> 7) ? 640 : 0;
      else if (o < 1280){ int q = (o-256) >> 8;  goff = 128 + (q&1)*128 + (q>>1)*640; }
      else              { int q = (o-1280) >> 8; goff = 384 + (q&1)*128 + (q>>1)*640; }
      P[o] *= gg[goff + h];
    }
    __syncthreads();
    for (int o = tid; o < 1152; o += 256){
      float s; int ch, c;
      if (o < 384){
        int g = o >> 7; c = o & 127;
        ch = (g==0) ? 0 : ((g==1) ? 2 : 6);
        const float* w0 = m0w2 + o;
        s = dot2W(P, P+128, w0, w0+49152, 384);
      } else if (o < 896){
        int om = o - 384; int tp = om >> 8; int col = om & 255;
        int g = col >> 7; c = col & 127;
        ch = tp ? (g ? 5 : 1) : (g ? 7 : 3);
        float sgn = tp ? 1.f : -1.f;
        const float* wr = m1w2r + col;
        const float* wi = m1w2i + col;
        s = dot2W(P+256+tp*128,     P+768+tp*128,     wr, wr+32768, 256)
          + sgn * dot2W(P+512+(1-tp)*128, P+1024+(1-tp)*128, wi, wi+32768, 256);
      } else {
        int om = o - 896; int tp = om >> 7; c = om & 127;
        ch = tp ? 4 : 8;
        float sgn = tp ? 1.f : -1.f;
        const float* wr = m2w2r + c;
        const float* wi = m2w2i + c;
        s = dot2W(P+1280+tp*128,     P+1792+tp*128,     wr, wr+16384, 128)
          + sgn * dot2W(P+1536+(1-tp)*128, P+2048+(1-tp)*128, wi, wi+16384, 128);
      }
      Yb[ch*128 + c] = s;
    }
    __syncthreads();
    {
      int half = tid >> 7, c = tid & 127;
      float z[9];
      #pragma unroll
      for (int i = 0; i < 9; i++) z[i] = 0.f;
      float y[9];
      #pragma unroll
      for (int i = 0; i < 9; i++) y[i] = Yb[i*128 + c];
      int p0 = half*162, p1 = p0 + 162;
      #pragma unroll 2
      for (int p = p0; p < p1; p++){
        float gp = 0.f;
        #pragma unroll
        for (int i = 0; i < 9; i++) gp += tg[p*9 + i] * y[i];
        float s = silu_f(gp);
        #pragma unroll
        for (int i = 0; i < 9; i++) z[i] += fg[p*9 + i] * s;
      }
      #pragma unroll
      for (int i = 0; i < 9; i++) Zb[half*1152 + i*128 + c] = z[i];
    }
    __syncthreads();
    for (int idx = tid; idx < 1152; idx += 256){
      int i2 = idx >> 7, c = idx & 127;
      float s = 0.f;
      #pragma unroll
      for (int j = 0; j < 9; j++)
        s += wl[j*9 + i2] * (Zb[j*128 + c] + Zb[1152 + j*128 + c]);
      acc[idx] += s;
    }
  }
  __syncthreads();
  {
    int o = tid;
    for (int i2 = 0; i2 < 9; i2++){
      int deg = d_DEG[i2];
      const float* wp = w_out + (size_t)deg*32768 + o;
      float s = (i2==0) ? b_out[o] : 0.f;
      #pragma unroll 4
      for (int c = 0; c < 128; c += 4){
        float4 a = *(const float4*)&acc[i2*128 + c];
        s += a.x*wp[(size_t)c*256] + a.y*wp[(size_t)(c+1)*256]
           + a.z*wp[(size_t)(c+2)*256] + a.w*wp[(size_t)(c+3)*256];
      }
      out[((size_t)n*9 + i2)*256 + o] = s;
    }
  }
}

// ---------------- host ----------------
extern "C" void kernel_launch(void* const* d_in, const int* in_sizes, int n_in,
                              void* d_out, int out_size, void* d_ws, size_t ws_size,
                              hipStream_t stream){
  const float* x     = (const float*)d_in[0];
  const float* attn  = (const float*)d_in[1];
  const float* wig   = (const float*)d_in[2];
  const float* tg    = (const float*)d_in[3];
  const float* fg    = (const float*)d_in[4];
  const float* w_in  = (const float*)d_in[5];
  const float* b_in  = (const float*)d_in[6];
  const float* w_out = (const float*)d_in[7];
  const float* b_out = (const float*)d_in[8];
  const float* es    = (const float*)d_in[9];
  const float* et    = (const float*)d_in[10];
  const float* fdw   = (const float*)d_in[11];
  const float* fdb   = (const float*)d_in[12];
  const float* few   = (const float*)d_in[13];
  const float* feb   = (const float*)d_in[14];
  const float* d0w   = (const float*)d_in[15];
  const float* d0b   = (const float*)d_in[16];
  const float* m0w1  = (const float*)d_in[17];
  const float* m0w2  = (const float*)d_in[18];
  const float* m1dw  = (const float*)d_in[19];
  const float* m1db  = (const float*)d_in[20];
  const float* m1w1r = (const float*)d_in[21];
  const float* m1w2r = (const float*)d_in[22];
  const float* m1w1i = (const float*)d_in[23];
  const float* m1w2i = (const float*)d_in[24];
  const float* m2dw  = (const float*)d_in[25];
  const float* m2db  = (const float*)d_in[26];
  const float* m2w1r = (const float*)d_in[27];
  const float* m2w2r = (const float*)d_in[28];
  const float* m2w1i = (const float*)d_in[29];
  const float* m2w2i = (const float*)d_in[30];
  const int*   an    = (const int*)d_in[31];
  const int*   esrc  = (const int*)d_in[32];
  const void*  maskp = d_in[33];

  int*   ip  = (int*)d_ws;
  int* FLAG  = ip + 0;
  int* COUNT = ip + 1;
  int* LIST  = ip + 16;                 // 4096 ints, ends at float offset 4112
  float* W   = (float*)d_ws;
  float* Hg1  = W + 4112;               // 589824 floats
  float* XEg1 = Hg1 + 589824;           // 65536
  float* XS1  = XEg1 + 65536;           // 2359296 floats
  float* XT1  = XS1 + 2359296;          // 2359296
  float* Gg1  = XT1 + 2359296;          // 2621440
  float* Pg1  = Gg1 + 2621440;          // 4718592
  float* Yf   = Pg1 + 4718592;          // 4718592
  float* Rf   = XS1;                    // 4718592 floats (XS1+XT1) — dead when gridm runs
  unsigned short* XSb = (unsigned short*)XS1;          // 4096*1152 ushorts
  unsigned short* XTb = (unsigned short*)XT1;
  unsigned short* Gbb = (unsigned short*)Gg1;          // 4096*1280
  unsigned short* Pgb = (unsigned short*)Pg1;          // 4096*2304
  unsigned short* Ybb = (unsigned short*)Yf;           // 4096*1152
  unsigned short* Wtb = Ybb + 4718592;                 // 655360
  unsigned short* tgAb = Wtb + 655360;                 // 11264
  unsigned short* fgAb = tgAb + 11264;                 // 5632
  size_t need_t1 = (size_t)(4112 + 589824 + 65536 + 2359296 + 2359296 + 2621440 + 4718592 + 4718592) * 4;

  k_detect<<<1,256,0,stream>>>((const unsigned int*)maskp, FLAG);

  if (ws_size >= need_t1){
    k_compact<<<1,256,0,stream>>>(maskp, FLAG, LIST, COUNT);
    k_h<<<dim3(32,9),128,0,stream>>>(x, w_in, b_in, Hg1);
    k_xe<<<16,256,0,stream>>>(attn, fdw, fdb, few, feb, es, et, an, esrc, XEg1);
    k_wcvt<<<576,256,0,stream>>>(m0w1, m1w1r, m1w1i, m2w1r, m2w1i,
                                 m0w2, m1w2r, m1w2i, m2w2r, m2w2i, Wtb);
    k_fprep<<<1,256,0,stream>>>(tg, fg, tgAb, fgAb);
    k_rotgate_m<<<4096,256,0,stream>>>(Hg1, XEg1, esrc, wig,
        d0w, d0b, m1dw, m1db, m2dw, m2db, XSb, XTb, Gbb, LIST, COUNT);
    k_gs1m<<<1152,256,0,stream>>>(XSb, XTb, Gbb, Wtb, Pgb, COUNT);
    k_gs2m<<<576,256,0,stream>>>(Pgb, Wtb + 294912, Ybb, COUNT);
    k_gridm<<<4096,256,0,stream>>>(Ybb, tgAb, fgAb, wig, LIST, COUNT, Rf);
    k_redout2<<<dim3(9,512),256,0,stream>>>(Rf, maskp, FLAG, w_out, b_out, (float*)d_out);
  } else {
    k_mega<<<512,256,0,stream>>>(
        x, w_in, b_in, attn, fdw, fdb, few, feb, es, et, an, esrc,
        d0w, d0b, m1dw, m1db, m2dw, m2db,
        m0w1, m0w2, m1w1r, m1w2r, m1w1i, m1w2i, m2w1r, m2w2r, m2w1i, m2w2i,
        wig, tg, fg, w_out, b_out, maskp, FLAG, (float*)d_out);
  }
}

// Round 22
// 254.121 us; speedup vs baseline: 1.0071x; 1.0071x over previous
//
#include <hip/hip_runtime.h>
#include <hip/hip_bf16.h>
#include <math.h>

typedef __attribute__((ext_vector_type(8))) short short8;
typedef __attribute__((ext_vector_type(4))) short short4_t;
typedef __attribute__((ext_vector_type(4))) float f32x4;

__device__ const int d_PERM[9] = {0,2,6,3,7,1,5,8,4};
__device__ const int d_DEG[9]  = {0,1,1,1,2,2,2,2,2};

__device__ __forceinline__ float silu_f(float x){ return x / (1.0f + __expf(-x)); }

__device__ __forceinline__ unsigned short f2bf(float f){
  __hip_bfloat16 h = __float2bfloat16(f);
  return __builtin_bit_cast(unsigned short, h);
}
__device__ __forceinline__ float bf2f(unsigned short b){
  return __uint_as_float(((unsigned int)b) << 16);
}

// flag: 0 = int32 words, 1 = u8 bytes, 2 = float32 words, 3 = int64 (low word)
__device__ __forceinline__ int mask_at(const void* mp, int flag, int e){
  if (flag==1) return ((const unsigned char*)mp)[e] != 0;
  if (flag==3) return ((const unsigned int*)mp)[2*e] != 0u;
  return ((const unsigned int*)mp)[e] != 0u;
}

__global__ void k_detect(const unsigned int* __restrict__ w, int* __restrict__ flag){
  __shared__ int notI, notF, anyOdd, anyEven;
  if (threadIdx.x==0){ notI=0; notF=0; anyOdd=0; anyEven=0; }
  __syncthreads();
  int li=0, lf=0, lo=0, le=0;
  for (int i = threadIdx.x; i < 1024; i += 256){
    unsigned int v = w[i];
    if (v != 0u && v != 1u) li = 1;
    if (v != 0u && v != 0x3F800000u) lf = 1;
    if (v != 0u){ if (i & 1) lo = 1; else le = 1; }
  }
  if (li) atomicOr(&notI,1);
  if (lf) atomicOr(&notF,1);
  if (lo) atomicOr(&anyOdd,1);
  if (le) atomicOr(&anyEven,1);
  __syncthreads();
  if (threadIdx.x==0){
    int f;
    if (!notI) f = (anyOdd || !anyEven) ? 0 : 3;
    else       f = (!notF) ? 2 : 1;
    *flag = f;
  }
}

__global__ __launch_bounds__(256) void k_compact(const void* __restrict__ maskp,
    const int* __restrict__ flagp, int* __restrict__ list, int* __restrict__ count){
  __shared__ int cnt[256];
  __shared__ int offs[256];
  int f = *flagp;
  int tid = threadIdx.x;
  int base = tid*16;
  int c = 0;
  for (int i=0;i<16;i++) if (!mask_at(maskp, f, base+i)) c++;
  cnt[tid] = c;
  __syncthreads();
  if (tid==0){
    int r = 0;
    for (int i=0;i<256;i++){ offs[i] = r; r += cnt[i]; }
    *count = r;
  }
  __syncthreads();
  int w = offs[tid];
  for (int i=0;i<16;i++){
    int e = base+i;
    if (!mask_at(maskp, f, e)) list[w++] = e;
  }
}

// ---------------- H = x @ w_in[DEG] (+b_in at j==0), (N,9,128) ----------------
__global__ __launch_bounds__(128) void k_h(const float* __restrict__ x,
    const float* __restrict__ w_in, const float* __restrict__ b_in,
    float* __restrict__ H){
  __shared__ float xl[16][260];
  int i = blockIdx.y; int n0 = blockIdx.x*16;
  int deg = d_DEG[i];
  for (int idx = threadIdx.x; idx < 16*256; idx += 128){
    int r = idx >> 8, c = idx & 255;
    xl[r][c] = x[((size_t)(n0+r)*9 + i)*256 + c];
  }
  __syncthreads();
  int o = threadIdx.x;
  float acc[16];
  #pragma unroll
  for (int r=0;r<16;r++) acc[r]=0.f;
  const float* w = w_in + (size_t)deg*32768 + o;
  for (int c=0;c<256;c+=4){
    float w0=w[(size_t)c*128], w1=w[(size_t)(c+1)*128], w2=w[(size_t)(c+2)*128], w3=w[(size_t)(c+3)*128];
    #pragma unroll
    for (int r=0;r<16;r++){
      float4 xv4 = *(const float4*)&xl[r][c];
      acc[r] += xv4.x*w0 + xv4.y*w1 + xv4.z*w2 + xv4.w*w3;
    }
  }
  float bb = (i==0)? b_in[o] : 0.f;
  #pragma unroll
  for (int r=0;r<16;r++) H[((size_t)(n0+r)*9+i)*128+o] = acc[r]+bb;
}

// ---------------- XE (E,16) ----------------
__global__ __launch_bounds__(256) void k_xe(const float* __restrict__ attn,
    const float* __restrict__ fdw, const float* __restrict__ fdb,
    const float* __restrict__ few, const float* __restrict__ feb,
    const float* __restrict__ es, const float* __restrict__ et,
    const int* __restrict__ an, const int* __restrict__ esrc,
    float* __restrict__ XE){
  int e = blockIdx.x*256 + threadIdx.x;
  float aw[32];
  #pragma unroll
  for (int k=0;k<32;k+=4){
    float4 v = *(const float4*)&attn[(size_t)e*32+k];
    aw[k]=v.x; aw[k+1]=v.y; aw[k+2]=v.z; aw[k+3]=v.w;
  }
  int src = esrc[e]; int tgt = e>>3;
  int za = an[src], zb = an[tgt];
  float v0[16];
  #pragma unroll
  for (int j=0;j<16;j++){
    float s = fdb[j] + es[(size_t)za*16+j] + et[(size_t)zb*16+j];
    #pragma unroll
    for (int k=0;k<32;k++) s += aw[k]*fdw[k*16+j];
    v0[j] = silu_f(s);
  }
  #pragma unroll
  for (int j=0;j<16;j++){
    float s = feb[j];
    #pragma unroll
    for (int k=0;k<16;k++) s += v0[k]*few[k*16+j];
    XE[(size_t)e*16+j] = silu_f(s);
  }
}

// ============ weight convert + transpose to bf16 [N][K] layouts ============
__global__ __launch_bounds__(256) void k_wcvt(
    const float* __restrict__ m0w1, const float* __restrict__ m1w1r, const float* __restrict__ m1w1i,
    const float* __restrict__ m2w1r, const float* __restrict__ m2w1i,
    const float* __restrict__ m0w2, const float* __restrict__ m1w2r, const float* __restrict__ m1w2i,
    const float* __restrict__ m2w2r, const float* __restrict__ m2w2i,
    unsigned short* __restrict__ Wt)
{
  int base = (blockIdx.x*256 + threadIdx.x)*4;
  #pragma unroll
  for (int ii = 0; ii < 4; ii++){
    int idx = base + ii;
    float v;
    if (idx < 98304){
      int p = idx/49152, r = idx%49152, n = r/384, k = r%384;
      v = m0w1[p*49152 + k*128 + n];
    } else if (idx < 229376){
      int j = idx-98304; int q = j/32768, r = j%32768, n = r/256, k = r%256;
      const float* w = (q&1)?m1w1i:m1w1r;
      v = w[(q>>1)*32768 + k*128 + n];
    } else if (idx < 294912){
      int j = idx-229376; int q = j/16384, r = j%16384, n = r/128, k = r%128;
      const float* w = (q&1)?m2w1i:m2w1r;
      v = w[(q>>1)*16384 + k*128 + n];
    } else if (idx < 393216){
      int j = idx-294912; int n = j/256, k = j%256;
      v = m0w2[(k>>7)*49152 + (k&127)*384 + n];
    } else if (idx < 524288){
      int j = idx-393216; int n = j/512, k = j%512;
      const float* w = ((k>>7)&1)?m1w2i:m1w2r;
      v = w[(k>>8)*32768 + (k&127)*256 + n];
    } else {
      int j = idx-524288; int n = j/512, k = j%512;
      const float* w = ((k>>7)&1)?m2w2i:m2w2r;
      v = w[(k>>8)*16384 + (k&127)*128 + n];
    }
    Wt[idx] = f2bf(v);
  }
}

// ============ grid-coefficient MFMA fragments (zero-padded) ============
__global__ __launch_bounds__(256) void k_fprep(const float* __restrict__ tg,
    const float* __restrict__ fg,
    unsigned short* __restrict__ tgA, unsigned short* __restrict__ fgA)
{
  for (int idx = threadIdx.x; idx < 11264; idx += 256){
    int pt = idx >> 9, rem = idx & 511, l = rem >> 3, j = rem & 7;
    int p = pt*16 + (l & 15);
    int i = (l >> 4)*8 + j;
    float v = (p < 324 && i < 9) ? tg[p*9 + i] : 0.f;
    tgA[idx] = f2bf(v);
  }
  for (int idx = threadIdx.x; idx < 5632; idx += 256){
    int sb = idx >> 9, rem = idx & 511, l = rem >> 3, j = rem & 7;
    int p = sb*32 + (l >> 4)*8 + j;
    int i = l & 15;
    float v = (p < 324 && i < 9) ? fg[p*9 + i] : 0.f;
    fgA[idx] = f2bf(v);
  }
}

// ================= rotate + gates (LDS-staged H, bf16 out, single chunk) ==========
__global__ __launch_bounds__(256) void k_rotgate_m(
    const float* __restrict__ Hg, const float* __restrict__ XEg,
    const int* __restrict__ esrc, const float* __restrict__ wig,
    const float* __restrict__ d0w,  const float* __restrict__ d0b,
    const float* __restrict__ m1dw, const float* __restrict__ m1db,
    const float* __restrict__ m2dw, const float* __restrict__ m2db,
    unsigned short* __restrict__ XSb, unsigned short* __restrict__ XTb,
    unsigned short* __restrict__ Gb,
    const int* __restrict__ list, const int* __restrict__ countp)
{
  int slot = blockIdx.x;
  if (slot >= *countp) return;
  __shared__ float HL[2304];
  __shared__ float wlr[81];
  __shared__ float xe16[16];
  int e = list[slot];
  int tid = threadIdx.x;
  int n = e >> 3, src = esrc[e];
  if (tid < 16) xe16[tid] = XEg[(size_t)e*16 + tid];
  for (int i = tid; i < 81; i += 256) wlr[i] = wig[(size_t)e*81 + i];
  {
    const float* hs = Hg + (size_t)src*1152;
    const float* ht = Hg + (size_t)n*1152;
    for (int idx = tid; idx < 1152; idx += 256){
      HL[idx]        = hs[idx];
      HL[1152 + idx] = ht[idx];
    }
  }
  __syncthreads();
  for (int idx = tid; idx < 1152; idx += 256){
    int p = idx >> 7, c = idx & 127;
    int ch = d_PERM[p];
    float s1 = 0.f, s2 = 0.f;
    #pragma unroll
    for (int j = 0; j < 9; j++){
      float wv = wlr[ch*9 + j];
      s1 += wv * HL[j*128 + c];
      s2 += wv * HL[1152 + j*128 + c];
    }
    XSb[(size_t)slot*1152 + idx] = f2bf(s1);
    XTb[(size_t)slot*1152 + idx] = f2bf(s2);
  }
  for (int col = tid; col < 1280; col += 256){
    int b = col / 640, r = col % 640;
    const float* w; float bias; int ldw, c2;
    if (r < 128){       w = d0w  + (size_t)b*2048; c2 = r;     ldw = 128; bias = d0b[b*128 + c2]; }
    else if (r < 384){  w = m1dw + (size_t)b*4096; c2 = r-128; ldw = 256; bias = m1db[b*256 + c2]; }
    else {              w = m2dw + (size_t)b*4096; c2 = r-384; ldw = 256; bias = m2db[b*256 + c2]; }
    float s = bias;
    #pragma unroll
    for (int kk = 0; kk < 16; kk++) s += xe16[kk] * w[kk*ldw + c2];
    Gb[(size_t)slot*1280 + col] = f2bf(silu_f(s));
  }
}

// ================= stage-1 MFMA GEMM (single chunk, 4096 slots) =================
__global__ __launch_bounds__(256) void k_gs1m(
    const unsigned short* __restrict__ XSb, const unsigned short* __restrict__ XTb,
    const unsigned short* __restrict__ Gb, const unsigned short* __restrict__ Wt,
    unsigned short* __restrict__ Pgb,
    const int* __restrict__ countp)
{
  int lc = *countp;
  if (lc <= 0) return;
  int b = blockIdx.x, t = threadIdx.x;
  const unsigned short* Ax; const unsigned short* Bw;
  int K, bm, obase, goff, rsh, aoff, tstride;
  if (b < 128){
    int path = b & 1, mt = b >> 1;
    Ax = path ? XTb : XSb;
    Bw = Wt + path*49152;
    K = 384; bm = mt*64; obase = path*128; goff = path ? 640 : 0;
    rsh = 0; aoff = 0; tstride = 0;
  } else if (b < 640){
    int i = b-128; int q = i>>7, mt = i&127;
    Ax = (q>=2) ? XTb : XSb;
    Bw = Wt + 98304 + q*32768;
    K = 256; bm = mt*64; obase = 256 + q*256; goff = 128 + (q&1)*128 + (q>>1)*640;
    rsh = 1; aoff = 384; tstride = 256;
  } else {
    int i = b-640; int q = i>>7, mt = i&127;
    Ax = (q>=2) ? XTb : XSb;
    Bw = Wt + 229376 + q*16384;
    K = 128; bm = mt*64; obase = 1280 + q*256; goff = 384 + (q&1)*128 + (q>>1)*640;
    rsh = 1; aoff = 896; tstride = 128;
  }
  int rows = rsh ? 2*lc : lc;
  if (bm >= rows) return;
  int w = t >> 6, l = t & 63;
  int am = bm + w*16 + (l & 15);
  int ael = am >> rsh, atp = am & rsh;
  const unsigned short* aptr = Ax + (size_t)ael*1152 + aoff + atp*tstride + ((l>>4)*8);
  int bn = l & 15;
  int bko = (l>>4)*8;
  f32x4 acc[8];
  #pragma unroll
  for (int i=0;i<8;i++){ acc[i][0]=0.f; acc[i][1]=0.f; acc[i][2]=0.f; acc[i][3]=0.f; }
  for (int k0 = 0; k0 < K; k0 += 32){
    short8 a = *(const short8*)(aptr + k0);
    #pragma unroll
    for (int nt = 0; nt < 8; nt++){
      const unsigned short* bp = Bw + (size_t)(nt*16 + bn)*K + k0 + bko;
      short8 bb = *(const short8*)bp;
      acc[nt] = __builtin_amdgcn_mfma_f32_16x16x32_bf16(a, bb, acc[nt], 0, 0, 0);
    }
  }
  #pragma unroll
  for (int nt = 0; nt < 8; nt++){
    #pragma unroll
    for (int r = 0; r < 4; r++){
      int i2 = (l>>4)*4 + r;
      int m = bm + w*16 + i2;
      int el = m >> rsh, tp = m & rsh;
      int h = nt*16 + (l & 15);
      float v = acc[nt][r] * bf2f(Gb[(size_t)el*1280 + goff + h]);
      Pgb[(size_t)el*2304 + obase + tp*128 + h] = f2bf(v);
    }
  }
}

// ================= stage-2 MFMA GEMM -> Ybb bf16 [slot][ch][c] (coalesced) =================
__global__ __launch_bounds__(256) void k_gs2m(
    const unsigned short* __restrict__ Pgb, const unsigned short* __restrict__ Wt2,
    unsigned short* __restrict__ Ybb,
    const int* __restrict__ countp)
{
  int lc = *countp;
  if (lc <= 0) return;
  int b = blockIdx.x, t = threadIdx.x;
  int region, bm, ncb, K, rsh, segb;
  const unsigned short* Bw;
  if (b < 192){ region=0; int mt=b/3, nt3=b-mt*3; bm=mt*64; ncb=nt3*128; K=256; rsh=0; segb=0;    Bw = Wt2; }
  else if (b < 448){ region=1; int i=b-192; int mt=i>>1, nt2=i&1; bm=mt*64; ncb=nt2*128; K=512; rsh=1; segb=256;  Bw = Wt2 + 98304; }
  else { region=2; int mt=b-448; bm=mt*64; ncb=0; K=512; rsh=1; segb=1280; Bw = Wt2 + 229376; }
  int rows = rsh ? 2*lc : lc;
  if (bm >= rows) return;
  int w = t >> 6, l = t & 63;
  int am = bm + w*16 + (l & 15);
  int ael = am >> rsh, atp = am & rsh;
  int bko = (l>>4)*8;
  f32x4 acc[8];
  #pragma unroll
  for (int i=0;i<8;i++){ acc[i][0]=0.f; acc[i][1]=0.f; acc[i][2]=0.f; acc[i][3]=0.f; }
  for (int k0 = 0; k0 < K; k0 += 32){
    const unsigned short* ap;
    short sm = 0;
    if (region == 0){
      ap = Pgb + (size_t)ael*2304 + k0 + bko;
    } else {
      int seg = k0 >> 7, kk = k0 & 127;
      int tsel = (seg&1) ? (1-atp) : atp;
      sm = (short)(((seg&1) && atp==0) ? 0x8000 : 0);
      ap = Pgb + (size_t)ael*2304 + segb + seg*256 + tsel*128 + kk + bko;
    }
    short8 a = *(const short8*)ap;
    short8 smv = (short8)sm;
    a ^= smv;
    #pragma unroll
    for (int nt = 0; nt < 8; nt++){
      const unsigned short* bp = Bw + (size_t)(ncb + nt*16 + (l&15))*K + k0 + bko;
      short8 bb = *(const short8*)bp;
      acc[nt] = __builtin_amdgcn_mfma_f32_16x16x32_bf16(a, bb, acc[nt], 0, 0, 0);
    }
  }
  #pragma unroll
  for (int nt = 0; nt < 8; nt++){
    #pragma unroll
    for (int r = 0; r < 4; r++){
      int i2 = (l>>4)*4 + r;
      int m = bm + w*16 + i2;
      int el = m >> rsh, tp = m & rsh;
      int col = ncb + nt*16 + (l&15);
      int g = col >> 7, c = col & 127;
      int ch;
      if (region==0)      ch = (g==0) ? 0 : ((g==1) ? 2 : 6);
      else if (region==1) ch = tp ? (g ? 5 : 1) : (g ? 7 : 3);
      else                ch = tp ? 4 : 8;
      Ybb[(size_t)el*1152 + ch*128 + c] = f2bf(acc[nt][r]);
    }
  }
}

// ================= MFMA grid transform: dual ct-chain; atomic accumulate into AT =========
__global__ __launch_bounds__(256) void k_gridm(
    const unsigned short* __restrict__ Ybb,
    const unsigned short* __restrict__ tgA, const unsigned short* __restrict__ fgA,
    const float* __restrict__ wig,
    const int* __restrict__ list, const int* __restrict__ countp,
    float* __restrict__ AT)
{
  int slot = blockIdx.x;
  if (slot >= *countp) return;
  __shared__ float wl[81];
  __shared__ unsigned short YL[128*24];
  __shared__ unsigned short Sld[2][4][640];
  __shared__ float Zld[4][256];
  int tid = threadIdx.x;
  int e = list[slot];
  int n = e >> 3;
  for (int i = tid; i < 81; i += 256) wl[i] = wig[(size_t)e*81 + i];
  for (int i = tid; i < 3072; i += 256) YL[i] = 0;
  __syncthreads();
  const unsigned short* ybase = Ybb + (size_t)slot*1152;
  for (int idx = tid; idx < 1152; idx += 256){
    int ch = idx >> 7, c = idx & 127;
    YL[c*24 + ch] = ybase[idx];
  }
  __syncthreads();
  int w = tid >> 6, l = tid & 63;
  int lcn = l & 15, lg = l >> 4;
  int c0a = (w*2 + 0)*16;
  int c0b = (w*2 + 1)*16;

  short8 bfA0 = (short8)(short)0, bfA1 = (short8)(short)0;
  if (lg < 2){
    bfA0 = *(const short8*)(&YL[(c0a + lcn)*24 + lg*8]);
    bfA1 = *(const short8*)(&YL[(c0b + lcn)*24 + lg*8]);
  }
  f32x4 Z0, Z1;
  Z0[0]=0.f; Z0[1]=0.f; Z0[2]=0.f; Z0[3]=0.f;
  Z1 = Z0;
  for (int sb = 0; sb < 11; sb++){
    f32x4 zr; zr[0]=0.f; zr[1]=0.f; zr[2]=0.f; zr[3]=0.f;
    short8 a0 = *(const short8*)(tgA + (size_t)(sb*2+0)*512 + l*8);
    short8 a1 = *(const short8*)(tgA + (size_t)(sb*2+1)*512 + l*8);
    f32x4 s00 = __builtin_amdgcn_mfma_f32_16x16x32_bf16(a0, bfA0, zr, 0, 0, 0);
    f32x4 s10 = __builtin_amdgcn_mfma_f32_16x16x32_bf16(a1, bfA0, zr, 0, 0, 0);
    f32x4 s01 = __builtin_amdgcn_mfma_f32_16x16x32_bf16(a0, bfA1, zr, 0, 0, 0);
    f32x4 s11 = __builtin_amdgcn_mfma_f32_16x16x32_bf16(a1, bfA1, zr, 0, 0, 0);
    short4_t pk00, pk10, pk01, pk11;
    #pragma unroll
    for (int r = 0; r < 4; r++){
      float v00 = s00[r]; v00 = v00 * __fdividef(1.0f, 1.0f + __expf(-v00));
      float v10 = s10[r]; v10 = v10 * __fdividef(1.0f, 1.0f + __expf(-v10));
      float v01 = s01[r]; v01 = v01 * __fdividef(1.0f, 1.0f + __expf(-v01));
      float v11 = s11[r]; v11 = v11 * __fdividef(1.0f, 1.0f + __expf(-v11));
      pk00[r] = (short)f2bf(v00);
      pk10[r] = (short)f2bf(v10);
      pk01[r] = (short)f2bf(v01);
      pk11[r] = (short)f2bf(v11);
    }
    *(short4_t*)&Sld[0][w][lcn*40 + lg*4]      = pk00;
    *(short4_t*)&Sld[0][w][lcn*40 + 16 + lg*4] = pk10;
    *(short4_t*)&Sld[1][w][lcn*40 + lg*4]      = pk01;
    *(short4_t*)&Sld[1][w][lcn*40 + 16 + lg*4] = pk11;
    short8 af = *(const short8*)(fgA + (size_t)sb*512 + l*8);
    short8 bs0 = *(const short8*)&Sld[0][w][lcn*40 + lg*8];
    short8 bs1 = *(const short8*)&Sld[1][w][lcn*40 + lg*8];
    Z0 = __builtin_amdgcn_mfma_f32_16x16x32_bf16(af, bs0, Z0, 0, 0, 0);
    Z1 = __builtin_amdgcn_mfma_f32_16x16x32_bf16(af, bs1, Z1, 0, 0, 0);
  }
  // stage D ct0: wigner^T then atomic accumulate into AT[n]
  {
    *(f32x4*)&Zld[w][lcn*16 + lg*4] = Z0;
    float zc[9];
    #pragma unroll
    for (int j = 0; j < 9; j++) zc[j] = Zld[w][lcn*16 + j];
    #pragma unroll
    for (int t2 = 0; t2 < 3; t2++){
      int i2 = lg + t2*4;
      if (i2 < 9){
        float r = 0.f;
        #pragma unroll
        for (int j = 0; j < 9; j++) r += wl[j*9 + i2] * zc[j];
        atomicAdd(&AT[(size_t)n*1152 + i2*128 + c0a + lcn], r);
      }
    }
  }
  // stage D ct1
  {
    *(f32x4*)&Zld[w][lcn*16 + lg*4] = Z1;
    float zc[9];
    #pragma unroll
    for (int j = 0; j < 9; j++) zc[j] = Zld[w][lcn*16 + j];
    #pragma unroll
    for (int t2 = 0; t2 < 3; t2++){
      int i2 = lg + t2*4;
      if (i2 < 9){
        float r = 0.f;
        #pragma unroll
        for (int j = 0; j < 9; j++) r += wl[j*9 + i2] * zc[j];
        atomicAdd(&AT[(size_t)n*1152 + i2*128 + c0b + lcn], r);
      }
    }
  }
}

// ================= w_out projection from AT (no mask, no reduce) =================
__global__ __launch_bounds__(256) void k_out2(const float* __restrict__ AT,
    const float* __restrict__ w_out, const float* __restrict__ b_out,
    float* __restrict__ out){
  __shared__ float sacc[128];
  int i2 = blockIdx.x; int n = blockIdx.y;
  int tid = threadIdx.x;
  if (tid < 128) sacc[tid] = AT[(size_t)n*1152 + i2*128 + tid];
  __syncthreads();
  int o = tid;
  int deg = d_DEG[i2];
  const float* wp = w_out + (size_t)deg*32768 + o;
  float s = (i2==0) ? b_out[o] : 0.f;
  #pragma unroll 4
  for (int c = 0; c < 128; c += 4){
    float4 a = *(const float4*)&sacc[c];
    s += a.x*wp[(size_t)c*256] + a.y*wp[(size_t)(c+1)*256]
       + a.z*wp[(size_t)(c+2)*256] + a.w*wp[(size_t)(c+3)*256];
  }
  out[((size_t)n*9 + i2)*256 + o] = s;
}

// ================= fallback mega kernel (round-5, pass-verified) =================
__device__ __forceinline__ float dotW(const float* __restrict__ A, const float* __restrict__ Wm, int K){
  float s = 0.f;
  #pragma unroll 4
  for (int i=0;i<K;i+=4){
    float4 a = *(const float4*)&A[i];
    s += a.x*Wm[(size_t)i*128] + a.y*Wm[(size_t)(i+1)*128]
       + a.z*Wm[(size_t)(i+2)*128] + a.w*Wm[(size_t)(i+3)*128];
  }
  return s;
}
__device__ __forceinline__ float dot2W(const float* __restrict__ P0, const float* __restrict__ P1,
    const float* __restrict__ W0, const float* __restrict__ W1, int ldw){
  float s = 0.f;
  #pragma unroll 4
  for (int k=0;k<128;k+=4){
    float4 a = *(const float4*)&P0[k];
    float4 b = *(const float4*)&P1[k];
    s += a.x*W0[(size_t)k*ldw] + a.y*W0[(size_t)(k+1)*ldw] + a.z*W0[(size_t)(k+2)*ldw] + a.w*W0[(size_t)(k+3)*ldw];
    s += b.x*W1[(size_t)k*ldw] + b.y*W1[(size_t)(k+1)*ldw] + b.z*W1[(size_t)(k+2)*ldw] + b.w*W1[(size_t)(k+3)*ldw];
  }
  return s;
}

__global__ __launch_bounds__(256) void k_mega(
    const float* __restrict__ x,      const float* __restrict__ w_in,  const float* __restrict__ b_in,
    const float* __restrict__ attn,
    const float* __restrict__ fdw,    const float* __restrict__ fdb,
    const float* __restrict__ few,    const float* __restrict__ feb,
    const float* __restrict__ es,     const float* __restrict__ et,
    const int*   __restrict__ an,     const int*   __restrict__ esrc,
    const float* __restrict__ d0w,    const float* __restrict__ d0b,
    const float* __restrict__ m1dw,   const float* __restrict__ m1db,
    const float* __restrict__ m2dw,   const float* __restrict__ m2db,
    const float* __restrict__ m0w1,   const float* __restrict__ m0w2,
    const float* __restrict__ m1w1r,  const float* __restrict__ m1w2r,
    const float* __restrict__ m1w1i,  const float* __restrict__ m1w2i,
    const float* __restrict__ m2w1r,  const float* __restrict__ m2w2r,
    const float* __restrict__ m2w1i,  const float* __restrict__ m2w2i,
    const float* __restrict__ wig,    const float* __restrict__ tg,   const float* __restrict__ fg,
    const float* __restrict__ w_out,  const float* __restrict__ b_out,
    const void*  __restrict__ maskp,  const int* __restrict__ flagp,
    float* __restrict__ out)
{
  __shared__ float S[7168];
  float* acc  = S;
  float* xs   = S + 1152;
  float* xtl  = S + 2304;
  float* Zb   = S + 1152;
  float* gg   = S + 3456;
  float* Yb   = S + 3456;
  float* P    = S + 4736;
  float* wl   = S + 7040;
  float* xe16 = S + 7124;
  float* xv   = S + 7140;

  const int n   = blockIdx.x;
  const int tid = threadIdx.x;
  const int f   = *flagp;

  for (int i = tid; i < 1152; i += 256) acc[i] = 0.f;

  for (int k = 0; k < 8; k++){
    int e = n*8 + k;
    if (mask_at(maskp, f, e)) continue;
    int src = esrc[e];
    __syncthreads();
    for (int i = tid; i < 81; i += 256) wl[i] = wig[(size_t)e*81 + i];
    if (tid < 16){
      int j = tid;
      float s = fdb[j] + es[(size_t)an[src]*16 + j] + et[(size_t)an[n]*16 + j];
      for (int kk = 0; kk < 32; kk++) s += attn[(size_t)e*32 + kk] * fdw[kk*16 + j];
      xv[j] = silu_f(s);
    }
    for (int idx = tid; idx < 2304; idx += 256){
      int which = idx >= 1152;
      int lidx = idx - which*1152;
      int j = lidx >> 7, c = lidx & 127;
      int deg = d_DEG[j];
      const float* wp = w_in + (size_t)deg*32768 + c;
      const float* xp = x + ((size_t)(which ? n : src)*9 + j)*256;
      float s = (j==0) ? b_in[c] : 0.f;
      for (int cc = 0; cc < 256; cc++) s += xp[cc] * wp[cc*128];
      P[idx] = s;
    }
    __syncthreads();
    if (tid < 16){
      int j = tid;
      float s = feb[j];
      for (int kk = 0; kk < 16; kk++) s += xv[kk] * few[kk*16 + j];
      xe16[j] = silu_f(s);
    }
    for (int idx = tid; idx < 1152; idx += 256){
      int p = idx >> 7, c = idx & 127;
      int ch = d_PERM[p];
      float s1 = 0.f, s2 = 0.f;
      #pragma unroll
      for (int j = 0; j < 9; j++){
        float wv = wl[ch*9 + j];
        s1 += wv * P[j*128 + c];
        s2 += wv * P[1152 + j*128 + c];
      }
      xs[idx]  = s1;
      xtl[idx] = s2;
    }
    __syncthreads();
    for (int col = tid; col < 1280; col += 256){
      int b = col / 640, r = col % 640;
      const float* w; float bias; int ldw, c2;
      if (r < 128){       w = d0w  + (size_t)b*2048; c2 = r;     ldw = 128; bias = d0b[b*128 + c2]; }
      else if (r < 384){  w = m1dw + (size_t)b*4096; c2 = r-128; ldw = 256; bias = m1db[b*256 + c2]; }
      else {              w = m2dw + (size_t)b*4096; c2 = r-384; ldw = 256; bias = m2db[b*256 + c2]; }
      float s = bias;
      #pragma unroll
      for (int kk = 0; kk < 16; kk++) s += xe16[kk] * w[kk*ldw + c2];
      gg[col] = silu_f(s);
    }
    __syncthreads();
    for (int o = tid; o < 2304; o += 256){
      float s;
      if (o < 256){
        int path = o >> 7, h = o & 127;
        s = dotW(path ? xtl : xs, m0w1 + (size_t)path*49152 + h, 384);
      } else if (o < 1280){
        int q = (o-256) >> 8; int rem = (o-256) & 255; int t = rem >> 7, h = rem & 127;
        const float* A  = ((q>=2) ? xtl : xs) + 384 + t*256;
        const float* Wm = ((q&1) ? m1w1i : m1w1r) + (size_t)((q>=2)?1:0)*32768 + h;
        s = dotW(A, Wm, 256);
      } else {
        int q = (o-1280) >> 8; int rem = (o-1280) & 255; int t = rem >> 7, h = rem & 127;
        const float* A  = ((q>=2) ? xtl : xs) + 896 + t*128;
        const float* Wm = ((q&1) ? m2w1i : m2w1r) + (size_t)((q>=2)?1:0)*16384 + h;
        s = dotW(A, Wm, 128);
      }
      P[o] = s;
    }
    __syncthreads();
    for (int o = tid; o < 2304; o += 256){
      int h = o & 127, goff;
      if (o < 256) goff = (o >> 7) ? 640 : 0;
      else if (o < 1280){ int q = (o-256) >> 8;  goff = 128 + (q&1)*128 + (q>>1)*640; }
      else              { int q = (o-1280) >> 8; goff = 384 + (q&1)*128 + (q>>1)*640; }
      P[o] *= gg[goff + h];
    }
    __syncthreads();
    for (int o = tid; o < 1152; o += 256){
      float s; int ch, c;
      if (o < 384){
        int g = o >> 7; c = o & 127;
        ch = (g==0) ? 0 : ((g==1) ? 2 : 6);
        const float* w0 = m0w2 + o;
        s = dot2W(P, P+128, w0, w0+49152, 384);
      } else if (o < 896){
        int om = o - 384; int tp = om >> 8; int col = om & 255;
        int g = col >> 7; c = col & 127;
        ch = tp ? (g ? 5 : 1) : (g ? 7 : 3);
        float sgn = tp ? 1.f : -1.f;
        const float* wr = m1w2r + col;
        const float* wi = m1w2i + col;
        s = dot2W(P+256+tp*128,     P+768+tp*128,     wr, wr+32768, 256)
          + sgn * dot2W(P+512+(1-tp)*128, P+1024+(1-tp)*128, wi, wi+32768, 256);
      } else {
        int om = o - 896; int tp = om >> 7; c = om & 127;
        ch = tp ? 4 : 8;
        float sgn = tp ? 1.f : -1.f;
        const float* wr = m2w2r + c;
        const float* wi = m2w2i + c;
        s = dot2W(P+1280+tp*128,     P+1792+tp*128,     wr, wr+16384, 128)
          + sgn * dot2W(P+1536+(1-tp)*128, P+2048+(1-tp)*128, wi, wi+16384, 128);
      }
      Yb[ch*128 + c] = s;
    }
    __syncthreads();
    {
      int half = tid >> 7, c = tid & 127;
      float z[9];
      #pragma unroll
      for (int i = 0; i < 9; i++) z[i] = 0.f;
      float y[9];
      #pragma unroll
      for (int i = 0; i < 9; i++) y[i] = Yb[i*128 + c];
      int p0 = half*162, p1 = p0 + 162;
      #pragma unroll 2
      for (int p = p0; p < p1; p++){
        float gp = 0.f;
        #pragma unroll
        for (int i = 0; i < 9; i++) gp += tg[p*9 + i] * y[i];
        float s = silu_f(gp);
        #pragma unroll
        for (int i = 0; i < 9; i++) z[i] += fg[p*9 + i] * s;
      }
      #pragma unroll
      for (int i = 0; i < 9; i++) Zb[half*1152 + i*128 + c] = z[i];
    }
    __syncthreads();
    for (int idx = tid; idx < 1152; idx += 256){
      int i2 = idx >> 7, c = idx & 127;
      float s = 0.f;
      #pragma unroll
      for (int j = 0; j < 9; j++)
        s += wl[j*9 + i2] * (Zb[j*128 + c] + Zb[1152 + j*128 + c]);
      acc[idx] += s;
    }
  }
  __syncthreads();
  {
    int o = tid;
    for (int i2 = 0; i2 < 9; i2++){
      int deg = d_DEG[i2];
      const float* wp = w_out + (size_t)deg*32768 + o;
      float s = (i2==0) ? b_out[o] : 0.f;
      #pragma unroll 4
      for (int c = 0; c < 128; c += 4){
        float4 a = *(const float4*)&acc[i2*128 + c];
        s += a.x*wp[(size_t)c*256] + a.y*wp[(size_t)(c+1)*256]
           + a.z*wp[(size_t)(c+2)*256] + a.w*wp[(size_t)(c+3)*256];
      }
      out[((size_t)n*9 + i2)*256 + o] = s;
    }
  }
}

// ---------------- host ----------------
extern "C" void kernel_launch(void* const* d_in, const int* in_sizes, int n_in,
                              void* d_out, int out_size, void* d_ws, size_t ws_size,
                              hipStream_t stream){
  const float* x     = (const float*)d_in[0];
  const float* attn  = (const float*)d_in[1];
  const float* wig   = (const float*)d_in[2];
  const float* tg    = (const float*)d_in[3];
  const float* fg    = (const float*)d_in[4];
  const float* w_in  = (const float*)d_in[5];
  const float* b_in  = (const float*)d_in[6];
  const float* w_out = (const float*)d_in[7];
  const float* b_out = (const float*)d_in[8];
  const float* es    = (const float*)d_in[9];
  const float* et    = (const float*)d_in[10];
  const float* fdw   = (const float*)d_in[11];
  const float* fdb   = (const float*)d_in[12];
  const float* few   = (const float*)d_in[13];
  const float* feb   = (const float*)d_in[14];
  const float* d0w   = (const float*)d_in[15];
  const float* d0b   = (const float*)d_in[16];
  const float* m0w1  = (const float*)d_in[17];
  const float* m0w2  = (const float*)d_in[18];
  const float* m1dw  = (const float*)d_in[19];
  const float* m1db  = (const float*)d_in[20];
  const float* m1w1r = (const float*)d_in[21];
  const float* m1w2r = (const float*)d_in[22];
  const float* m1w1i = (const float*)d_in[23];
  const float* m1w2i = (const float*)d_in[24];
  const float* m2dw  = (const float*)d_in[25];
  const float* m2db  = (const float*)d_in[26];
  const float* m2w1r = (const float*)d_in[27];
  const float* m2w2r = (const float*)d_in[28];
  const float* m2w1i = (const float*)d_in[29];
  const float* m2w2i = (const float*)d_in[30];
  const int*   an    = (const int*)d_in[31];
  const int*   esrc  = (const int*)d_in[32];
  const void*  maskp = d_in[33];

  int*   ip  = (int*)d_ws;
  int* FLAG  = ip + 0;
  int* COUNT = ip + 1;
  int* LIST  = ip + 16;                 // 4096 ints, ends at float offset 4112
  float* W   = (float*)d_ws;
  float* Hg1  = W + 4112;               // 589824 floats
  float* XEg1 = Hg1 + 589824;           // 65536
  float* XS1  = XEg1 + 65536;           // 2359296 floats
  float* XT1  = XS1 + 2359296;          // 2359296
  float* Gg1  = XT1 + 2359296;          // 2621440
  float* Pg1  = Gg1 + 2621440;          // 4718592
  float* Yf   = Pg1 + 4718592;          // 4718592
  float* ATf  = XS1;                    // 589824 floats (atom accumulator) — XS1 dead when gridm runs
  unsigned short* XSb = (unsigned short*)XS1;          // 4096*1152 ushorts
  unsigned short* XTb = (unsigned short*)XT1;
  unsigned short* Gbb = (unsigned short*)Gg1;          // 4096*1280
  unsigned short* Pgb = (unsigned short*)Pg1;          // 4096*2304
  unsigned short* Ybb = (unsigned short*)Yf;           // 4096*1152
  unsigned short* Wtb = Ybb + 4718592;                 // 655360
  unsigned short* tgAb = Wtb + 655360;                 // 11264
  unsigned short* fgAb = tgAb + 11264;                 // 5632
  size_t need_t1 = (size_t)(4112 + 589824 + 65536 + 2359296 + 2359296 + 2621440 + 4718592 + 4718592) * 4;

  k_detect<<<1,256,0,stream>>>((const unsigned int*)maskp, FLAG);

  if (ws_size >= need_t1){
    k_compact<<<1,256,0,stream>>>(maskp, FLAG, LIST, COUNT);
    k_h<<<dim3(32,9),128,0,stream>>>(x, w_in, b_in, Hg1);
    k_xe<<<16,256,0,stream>>>(attn, fdw, fdb, few, feb, es, et, an, esrc, XEg1);
    k_wcvt<<<576,256,0,stream>>>(m0w1, m1w1r, m1w1i, m2w1r, m2w1i,
                                 m0w2, m1w2r, m1w2i, m2w2r, m2w2i, Wtb);
    k_fprep<<<1,256,0,stream>>>(tg, fg, tgAb, fgAb);
    k_rotgate_m<<<4096,256,0,stream>>>(Hg1, XEg1, esrc, wig,
        d0w, d0b, m1dw, m1db, m2dw, m2db, XSb, XTb, Gbb, LIST, COUNT);
    k_gs1m<<<1152,256,0,stream>>>(XSb, XTb, Gbb, Wtb, Pgb, COUNT);
    k_gs2m<<<576,256,0,stream>>>(Pgb, Wtb + 294912, Ybb, COUNT);
    hipMemsetAsync(ATf, 0, (size_t)589824*4, stream);   // zero AT (XS1 dead after gs1m)
    k_gridm<<<4096,256,0,stream>>>(Ybb, tgAb, fgAb, wig, LIST, COUNT, ATf);
    k_out2<<<dim3(9,512),256,0,stream>>>(ATf, w_out, b_out, (float*)d_out);
  } else {
    k_mega<<<512,256,0,stream>>>(
        x, w_in, b_in, attn, fdw, fdb, few, feb, es, et, an, esrc,
        d0w, d0b, m1dw, m1db, m2dw, m2db,
        m0w1, m0w2, m1w1r, m1w2r, m1w1i, m1w2i, m2w1r, m2w2r, m2w1i, m2w2i,
        wig, tg, fg, w_out, b_out, maskp, FLAG, (float*)d_out);
  }
}